// Round 14
// baseline (343.825 us; speedup 1.0000x reference)
//
#include <hip/hip_runtime.h>
#include <stdint.h>

#define EPSF 1e-4f

typedef int v4i __attribute__((ext_vector_type(4)));

// ---------------- workspace layout (bytes) ----------------
#define OFF_SCALES 0            // 576 per-block absmax partials (9 layers x 64)
#define OFF_FOLD   4096         // folded BN params (3840 floats)
#define OFF_W      32768        // B-fragment weights (MFMA lane order)
#define OFF_TF2    (OFF_W + 1548288)   // fc2 ternary [10][512]
#define OFF_ACT_A  2097152
#define OFF_ACT_B  60817408
#define OFF_PART   134217728    // K-split i32 partials (conv5: 4.2 MB)

static const int FOLD_OFF_H[8] = {0,128,256,512,768,1280,1792,2816};
__device__ __constant__ int FOLD_OFF_D[8] = {0,128,256,512,768,1280,1792,2816};

// per-layer B-frag prep tables: l0..5 = conv0..5, l6=fc0, l7=fc1
// conv0 (mode 0) is the 4B-packed-input variant: K=64 = ky(quad) x dx x ci4
__device__ __constant__ int PREP_MODE[8] = {0,1,1,1,1,1,2,2};
__device__ __constant__ int PREP_CO[8]   = {64,64,128,128,256,256,512,512};
__device__ __constant__ int PREP_CI[8]   = {3,64,64,128,128,256,256,512};
__device__ __constant__ int PREP_KC[8]   = {1,1,1,2,2,4,1,1};
__device__ __constant__ int PREP_OFF[8]  = {0,4096,40960,114688,262144,557056,1146880,1277952};
// end of packed weights = 1540096 bytes -> 6016 blocks

#define NB_BPREP 6016
#define NB_TERN  20
#define NB_FOLD  16

// reduce a layer's 64 absmax partials (written by absmax_all_k, no atomics)
__device__ __forceinline__ float get_scale(const float* p, int l) {
    float m = p[l * 64];
#pragma unroll 63
    for (int i = 1; i < 64; ++i) m = fmaxf(m, p[l * 64 + i]);
    return m;
}

// ---------------- prep kernels ----------------
// absmax: per-block partial max -> distinct slot (no zero-init, no atomics)
struct AbsArgs { const float* w[9]; int n[9]; };
__global__ void absmax_all_k(AbsArgs a, float* partials) {
    __shared__ float red[256];
    int l = blockIdx.x >> 6;
    int sb = blockIdx.x & 63;
    const float* w = a.w[l];
    int n = a.n[l];
    float m = 0.f;
    for (int i = sb * 256 + threadIdx.x; i < n; i += 64 * 256)
        m = fmaxf(m, fabsf(w[i]));
    red[threadIdx.x] = m;
    __syncthreads();
    for (int s2 = 128; s2 > 0; s2 >>= 1) {
        if ((int)threadIdx.x < s2) red[threadIdx.x] = fmaxf(red[threadIdx.x], red[threadIdx.x + s2]);
        __syncthreads();
    }
    if (threadIdx.x == 0) partials[l * 64 + sb] = red[0];
}

// merged prep: [bprep | tern_fc2 | bnfold | quant_in] by block region.
struct PrepArgs {
    const float* w[8];        // conv0..5, fc0, fc1
    const float* fw2;
    const float* x;           // input images
    const float* bg[8]; const float* bb[8]; const float* bm[8]; const float* bv[8];
};
__global__ void megaprep_k(PrepArgs pa, const float* __restrict__ partials,
                           int8_t* __restrict__ dst, int8_t* __restrict__ tf2,
                           float* __restrict__ fold, int* __restrict__ qout, int B) {
    int b = blockIdx.x;
    if (b < NB_BPREP) {
        int gidx = b * 256 + threadIdx.x;
        int l = 0;
#pragma unroll
        for (int i = 1; i < 8; ++i) l += (gidx >= PREP_OFF[i]) ? 1 : 0;
        int idx = gidx - PREP_OFF[l];
        const float* w = pa.w[l];
        float s = get_scale(partials, l);
        int jb = idx & 15;
        int lane = (idx >> 4) & 63;
        int fct = idx >> 10;
        int quad = lane >> 4, n = lane & 15;
        int COT = PREP_CO[l] >> 4;
        int ct = fct & (COT - 1);
        int st = fct >> (31 - __clz(COT));
        int co = (ct >> 2) * 64 + (ct & 3) + 4 * n;   // ct-interleaved
        float val;
        int md = PREP_MODE[l];
        if (md == 0) {
            int ky = quad, dx = jb >> 2, ci = jb & 3;
            val = (ky < 3 && dx < 3 && ci < 3) ? w[(co * 3 + ci) * 9 + ky * 3 + dx] : 0.f;
        } else if (md == 1) {
            int KC = PREP_KC[l], CI = PREP_CI[l];
            int kxy = st / KC, kc = st - kxy * KC;
            int ci = kc * 64 + quad * 16 + jb;
            val = w[(co * CI + ci) * 9 + kxy];
        } else {
            int CI = PREP_CI[l];
            int i = st * 64 + quad * 16 + jb;
            val = w[co * CI + i];
        }
        float q = fminf(fmaxf(rintf(val / s), -1.f), 1.f);
        dst[gidx] = (int8_t)q;
    } else if (b < NB_BPREP + NB_TERN) {
        int i = (b - NB_BPREP) * 256 + threadIdx.x;   // < 5120 exact
        float s = get_scale(partials, 8);
        float q = fminf(fmaxf(rintf(pa.fw2[i] / s), -1.f), 1.f);
        tf2[i] = (int8_t)q;
    } else if (b < NB_BPREP + NB_TERN + NB_FOLD) {
        int rel = b - NB_BPREP - NB_TERN;             // 0..15
        int l = rel >> 1;
        int i = (rel & 1) * 256 + threadIdx.x;
        int CO = PREP_CO[l];
        if (i >= CO) return;
        float s = get_scale(partials, l);
        float sc = pa.bg[l][i] / sqrtf(pa.bv[l][i] + EPSF);
        float s_in = (l == 0) ? 0.0078125f : 1.0f;
        fold[FOLD_OFF_D[l] + i] = s_in * s * sc;
        fold[FOLD_OFF_D[l] + CO + i] = pa.bb[l][i] - pa.bm[l][i] * sc;
    } else {
        int idx = (b - NB_BPREP - NB_TERN - NB_FOLD) * 256 + threadIdx.x;
        if (idx >= B * 1024) return;
        int p = idx & 1023;
        int bb2 = idx >> 10;
        unsigned pk = 0;
#pragma unroll
        for (int c = 0; c < 3; ++c) {
            float q = rintf(pa.x[((size_t)bb2 * 3 + c) * 1024 + p] * 128.f);
            q = fminf(fmaxf(q, -127.f), 127.f);
            pk |= ((unsigned)((int)q & 0xff)) << (8 * c);
        }
        qout[idx] = (int)pk;
    }
}

// K-split reduce: sum SP i32 partials, BN + 2-bit quant, pack 4 co/dword.
__global__ void ksum_bn_k(const int4* __restrict__ part, const float* __restrict__ fold,
                          int8_t* __restrict__ out, int NPOS, int CO, int SP) {
    int idx = blockIdx.x * 256 + threadIdx.x;
    int n4 = CO >> 2;
    if (idx >= NPOS * n4) return;
    int c4 = idx % n4, pos = idx / n4;
    int4 s = make_int4(0, 0, 0, 0);
    for (int sp = 0; sp < SP; ++sp) {
        int4 p = part[(size_t)(sp * NPOS + pos) * n4 + c4];
        s.x += p.x; s.y += p.y; s.z += p.z; s.w += p.w;
    }
    int co = c4 * 4;
    const int* sv = (const int*)&s;
    unsigned pk = 0;
#pragma unroll
    for (int k = 0; k < 4; ++k) {
        float h = (float)sv[k] * fold[co + k] + fold[CO + co + k];
        int q = (int)fminf(fmaxf(rintf(h), -1.f), 1.f);
        pk |= ((unsigned)(q & 0xff)) << (8 * k);
    }
    *(int*)&out[(size_t)pos * CO + co] = (int)pk;
}

// ---------------- MFMA implicit-GEMM conv/FC ----------------
// CHP: LDS chunk size (steps). CHP==NSTEP -> fully-resident B (one stage,
// ONE barrier, uninterrupted AD pipeline) -- the twice-proven path, now also
// used for NSTEP=18 layers (conv3/conv4: 72KB LDS, 2 blocks/CU) instead of
// the 2-phase chunked path (2 stages + 4 barriers + mid-loop vmcnt drain).
template<int CO, int NSTEP, int KC, int KXN, int CI, int IH, int IW, int OW,
         int NPOS1, int J, int NCT, int COG, int MINW, int ITER, int AD, int SP,
         int QSTRIDE, int CHP>
__global__ __launch_bounds__(256, MINW) void mfconv_k(
        const int8_t* __restrict__ act, const int8_t* __restrict__ bf,
        const float* __restrict__ fold, int8_t* __restrict__ out, int NPOS) {
    static_assert(NCT == 4, "epilogue packs 4 cotiles per dword");
    constexpr int COT = CO / 16;
    constexpr int CH = CHP;                       // steps per LDS chunk
    constexpr int NCHK = NSTEP / CH;
    static_assert(NSTEP % CH == 0, "chunking must be exact");
    static_assert(AD == 1 || AD == 2, "A-lookahead depth");
    static_assert((ITER == 1 && AD == 1) || NCHK == 1,
                  "ITER/AD need resident B");
    static_assert(AD == 1 || NSTEP % 3 == 0, "ring-3 phase proof");
    static_assert(ITER == 1 || AD == 2 || (NSTEP & 1) == 1,
                  "AD=1 ITER path needs odd NSTEP (buffer parity proof)");
    static_assert(SP == 1 || (NCHK == 1 && ITER == 1), "K-split: resident B");
    __shared__ __align__(16) int8_t lds[CH * NCT * 1024];

    int lane = threadIdx.x & 63;
    int wid = threadIdx.x >> 6;
    int nb = (int)gridDim.x;
    int b0 = (int)blockIdx.x;
    int bsw = (nb & 7) ? b0 : ((b0 & 7) * (nb >> 3) + (b0 >> 3));
    int w = bsw * 4 + wid;                        // grid is exact: no tail waves
    int PGi = NPOS / (16 * J) / ITER;             // pg-groups per wave
    int pgw = w % PGi;
    int cgsp = w / PGi;
    int cg = cgsp % COG;                          // block-uniform (PGi%4==0)
    int sp = cgsp / COG;                          // block-uniform K-split slot
    constexpr int sStep = NSTEP;
    int sBase = sp * sStep;
    int m = lane & 15, quad = lane >> 4;

    float Af[NCT], Bf[NCT];
#pragma unroll
    for (int ct = 0; ct < NCT; ++ct) {
        int co = cg * 64 + ct + 4 * m;
        Af[ct] = fold[co];
        Bf[ct] = fold[CO + co];
    }

    const int8_t* ab[J];
    auto setA = [&](int pos0) {
#pragma unroll
        for (int j = 0; j < J; ++j) {
            int pos = pos0 + j * 16 + m;
            int img = pos / NPOS1, p = pos - img * NPOS1;
            int oy = p / OW, ox = p - oy * OW;
            ab[j] = act + (size_t)((img * IH + oy) * IW + ox) * CI + quad * QSTRIDE;
        }
    };
    auto ldA = [&](int s, v4i* dst) {             // s is ABSOLUTE step
        int kxy = s / KC, kc = s - kxy * KC;
        int ky = kxy / KXN, kx = kxy - ky * KXN;
        int off = (ky * IW + kx) * CI + kc * 64;
#pragma unroll
        for (int j = 0; j < J; ++j) dst[j] = *(const v4i*)(ab[j] + off);
    };
    auto ldB = [&](int ls, v4i* dst) {            // ls is LOCAL (LDS slot)
#pragma unroll
        for (int ct = 0; ct < NCT; ++ct)
            dst[ct] = *(const v4i*)&lds[(ls * NCT + ct) * 1024 + lane * 16];
    };
    auto stageB = [&](int s0) {                   // s0 is ABSOLUTE
#pragma unroll
        for (int ls = 0; ls < CH; ++ls) {
            const int8_t* src = bf + ((size_t)((s0 + ls) * COT) + cg * NCT) * 1024;
#pragma unroll
            for (int k = 0; k < NCT / 4; ++k)
                *(v4i*)&lds[ls * NCT * 1024 + (k * 256 + (int)threadIdx.x) * 16] =
                    *(const v4i*)(src + (k * 256 + (int)threadIdx.x) * 16);
        }
    };
    auto finish = [&](int pos0, v4i (&acc)[J][NCT]) {
        if (SP == 1) {
#pragma unroll
            for (int j = 0; j < J; ++j) {
#pragma unroll
                for (int r = 0; r < 4; ++r) {
                    unsigned pk = 0;
#pragma unroll
                    for (int ct = 0; ct < NCT; ++ct) {
                        float h = (float)acc[j][ct][r] * Af[ct] + Bf[ct];
                        int q = (int)fminf(fmaxf(rintf(h), -1.f), 1.f);
                        pk |= ((unsigned)(q & 0xff)) << (8 * ct);
                    }
                    *(int*)&out[(size_t)(pos0 + j * 16 + quad * 4 + r) * CO + cg * 64 + 4 * m] = (int)pk;
                }
            }
        } else {
            int* part = (int*)out;
#pragma unroll
            for (int j = 0; j < J; ++j) {
#pragma unroll
                for (int r = 0; r < 4; ++r) {
                    v4i pv;
#pragma unroll
                    for (int ct = 0; ct < NCT; ++ct) pv[ct] = acc[j][ct][r];
                    *(v4i*)&part[(size_t)(sp * NPOS + pos0 + j * 16 + quad * 4 + r) * CO + cg * 64 + 4 * m] = pv;
                }
            }
        }
    };

    v4i Ab[3][J], Bb[2][NCT];

    if (NCHK == 1) {
        int pg = pgw * ITER;
        int pos0 = pg * (16 * J);
        setA(pos0);
        ldA(sBase + 0, Ab[0]);
        if (AD == 2 && NSTEP > 1) ldA(sBase + 1, Ab[1]);
        stageB(sBase);
        __syncthreads();                          // the ONLY barrier
#pragma unroll
        for (int it = 0; it < ITER; ++it) {
            v4i acc[J][NCT] = {};
            ldB(0, Bb[0]);
            if (AD == 2) {
#pragma unroll
                for (int ls = 0; ls < NSTEP; ++ls) {
                    if (ls + 2 < NSTEP) ldA(sBase + ls + 2, Ab[(ls + 2) % 3]);
                    if (ls + 1 < NSTEP) ldB(ls + 1, Bb[(ls + 1) & 1]);
                    __builtin_amdgcn_sched_barrier(0);
#pragma unroll
                    for (int j = 0; j < J; ++j)
#pragma unroll
                        for (int ct = 0; ct < NCT; ++ct)
                            acc[j][ct] = __builtin_amdgcn_mfma_i32_16x16x64_i8(
                                Ab[ls % 3][j], Bb[ls & 1][ct], acc[j][ct], 0, 0, 0);
                }
                int pos0n = pos0;
                if (it + 1 < ITER) {
                    pos0n = (pg + it + 1) * (16 * J);
                    setA(pos0n);
                    ldA(sBase + 0, Ab[0]);
                    ldA(sBase + 1, Ab[1]);
                }
                __builtin_amdgcn_sched_barrier(0);
                finish(pos0, acc);
                pos0 = pos0n;
            } else {
                const int p = (it & 1) & (NSTEP & 1);
#pragma unroll
                for (int ls = 0; ls < NSTEP; ++ls) {
                    if (ls + 1 < NSTEP) {
                        ldA(sBase + ls + 1, Ab[(ls + 1 + p) & 1]);
                        ldB(ls + 1, Bb[(ls + 1) & 1]);
                    }
                    __builtin_amdgcn_sched_barrier(0);
#pragma unroll
                    for (int j = 0; j < J; ++j)
#pragma unroll
                        for (int ct = 0; ct < NCT; ++ct)
                            acc[j][ct] = __builtin_amdgcn_mfma_i32_16x16x64_i8(
                                Ab[(ls + p) & 1][j], Bb[ls & 1][ct], acc[j][ct], 0, 0, 0);
                }
                int pos0n = pos0;
                if (it + 1 < ITER) {
                    pos0n = (pg + it + 1) * (16 * J);
                    setA(pos0n);
                    ldA(sBase + 0, Ab[(p ^ 1) & 1]);
                }
                __builtin_amdgcn_sched_barrier(0);
                finish(pos0, acc);
                pos0 = pos0n;
            }
        }
    } else {
        int pos0 = pgw * (16 * J);
        setA(pos0);
        v4i acc[J][NCT] = {};
#pragma unroll
        for (int c = 0; c < NCHK; ++c) {
            int s0 = c * CH;
            ldA(s0, Ab[s0 & 1]);
            __syncthreads();
            stageB(s0);
            __syncthreads();
            ldB(0, Bb[0]);
#pragma unroll
            for (int ls = 0; ls < CH; ++ls) {
                int s = s0 + ls;
                int cb = s & 1, nb2 = cb ^ 1;
                if (ls + 1 < CH) {
                    ldA(s + 1, Ab[nb2]);
                    ldB(ls + 1, Bb[(ls + 1) & 1]);
                }
                __builtin_amdgcn_sched_barrier(0);
#pragma unroll
                for (int j = 0; j < J; ++j)
#pragma unroll
                    for (int ct = 0; ct < NCT; ++ct)
                        acc[j][ct] = __builtin_amdgcn_mfma_i32_16x16x64_i8(
                            Ab[cb][j], Bb[ls & 1][ct], acc[j][ct], 0, 0, 0);
            }
        }
        finish(pos0, acc);
    }
}

// ---------------- pool (int4: 16 channels per thread) ----------------
__global__ void pool_k(const int8_t* __restrict__ a, int8_t* __restrict__ o,
                       int B, int C, int IH, int IW, int OH, int OW) {
    int idx = blockIdx.x * blockDim.x + threadIdx.x;
    int c16n = C >> 4;
    int total = B * OH * OW * c16n;
    if (idx >= total) return;
    int c16 = idx % c16n;
    int t1 = idx / c16n;
    int ox = t1 % OW;
    int t2 = t1 / OW;
    int oy = t2 % OH;
    int b = t2 / OH;
    const int8_t* p = a + (((size_t)b * IH + 2 * oy) * IW + 2 * ox) * C + 16 * c16;
    int4 w0 = *(const int4*)p;
    int4 w1 = *(const int4*)(p + C);
    int4 w2 = *(const int4*)(p + (size_t)IW * C);
    int4 w3 = *(const int4*)(p + (size_t)IW * C + C);
    int4 r;
    const int* a0 = (const int*)&w0; const int* a1 = (const int*)&w1;
    const int* a2 = (const int*)&w2; const int* a3 = (const int*)&w3;
    int* rr = (int*)&r;
#pragma unroll
    for (int d = 0; d < 4; ++d) {
        unsigned v = 0;
#pragma unroll
        for (int k = 0; k < 4; ++k) {
            int x0 = (int)(int8_t)(a0[d] >> (8 * k));
            int x1 = (int)(int8_t)(a1[d] >> (8 * k));
            int x2 = (int)(int8_t)(a2[d] >> (8 * k));
            int x3 = (int)(int8_t)(a3[d] >> (8 * k));
            int mx = max(max(x0, x1), max(x2, x3));
            v |= ((unsigned)(mx & 0xff)) << (8 * k);
        }
        rr[d] = (int)v;
    }
    *(int4*)(o + (((size_t)b * OH + oy) * OW + ox) * C + 16 * c16) = r;
}

__device__ __forceinline__ int dot4(int a, int b, int c) {
#if __has_builtin(__builtin_amdgcn_sdot4)
    return __builtin_amdgcn_sdot4(a, b, c, false);
#else
    c += (int)(int8_t)(a) * (int)(int8_t)(b);
    c += (int)(int8_t)(a >> 8)  * (int)(int8_t)(b >> 8);
    c += (int)(int8_t)(a >> 16) * (int)(int8_t)(b >> 16);
    c += (int)(int8_t)(a >> 24) * (int)(int8_t)(b >> 24);
    return c;
#endif
}

// final FC + tensor norm -> float out; reduces fc2 scale from partials inline
__global__ void fc_out_k(const int8_t* __restrict__ a, const int8_t* __restrict__ t,
                         const float* __restrict__ partials,
                         const float* __restrict__ tw, const float* __restrict__ tb,
                         const float* __restrict__ tm, const float* __restrict__ tv,
                         float* __restrict__ out, int B, int I, int O) {
    int idx = blockIdx.x * blockDim.x + threadIdx.x;
    if (idx >= B * O) return;
    int o = idx % O;
    int b = idx / O;
    const int* ar = (const int*)(a + (size_t)b * I);
    const int* tr = (const int*)(t + (size_t)o * I);
    int acc = 0;
    for (int i = 0; i < (I >> 2); ++i) acc = dot4(ar[i], tr[i], acc);
    float s8 = get_scale(partials, 8);
    float sc = tw[0] / sqrtf(tv[0] + EPSF);
    out[idx] = ((float)acc * s8 - tm[0]) * sc + tb[0];
}

static inline unsigned cdiv(long long a, int b) { return (unsigned)((a + b - 1) / b); }

extern "C" void kernel_launch(void* const* d_in, const int* in_sizes, int n_in,
                              void* d_out, int out_size, void* d_ws, size_t ws_size,
                              hipStream_t stream) {
    const float* x = (const float*)d_in[0];
    const float* cw[6]; const float* bng[6]; const float* bnb[6];
    const float* bnm[6]; const float* bnv[6];
    for (int l = 0; l < 6; ++l) {
        cw[l]  = (const float*)d_in[1 + 5 * l + 0];
        bng[l] = (const float*)d_in[1 + 5 * l + 1];
        bnb[l] = (const float*)d_in[1 + 5 * l + 2];
        bnm[l] = (const float*)d_in[1 + 5 * l + 3];
        bnv[l] = (const float*)d_in[1 + 5 * l + 4];
    }
    const float* fw0 = (const float*)d_in[31];
    const float* fw1 = (const float*)d_in[32];
    const float* fw2 = (const float*)d_in[33];
    const float* fbn[2][4] = {
        { (const float*)d_in[34], (const float*)d_in[35], (const float*)d_in[36], (const float*)d_in[37] },
        { (const float*)d_in[38], (const float*)d_in[39], (const float*)d_in[40], (const float*)d_in[41] } };
    const float* tn_w = (const float*)d_in[42];
    const float* tn_b = (const float*)d_in[43];
    const float* tn_m = (const float*)d_in[44];
    const float* tn_v = (const float*)d_in[45];

    char* ws = (char*)d_ws;
    float* scales = (float*)(ws + OFF_SCALES);    // 576 partials
    float* fold = (float*)(ws + OFF_FOLD);
    int8_t* bfw = (int8_t*)(ws + OFF_W);
    int8_t* tf2 = (int8_t*)(ws + OFF_TF2);
    int8_t* actA = (int8_t*)(ws + OFF_ACT_A);
    int8_t* actB = (int8_t*)(ws + OFF_ACT_B);
    int8_t* partW = (int8_t*)(ws + OFF_PART);

    const int B = in_sizes[0] / 3072;

    AbsArgs aa;
    aa.w[0]=cw[0]; aa.w[1]=cw[1]; aa.w[2]=cw[2]; aa.w[3]=cw[3]; aa.w[4]=cw[4]; aa.w[5]=cw[5];
    aa.w[6]=fw0; aa.w[7]=fw1; aa.w[8]=fw2;
    aa.n[0]=64*3*9; aa.n[1]=64*64*9; aa.n[2]=128*64*9; aa.n[3]=128*128*9;
    aa.n[4]=256*128*9; aa.n[5]=256*256*9; aa.n[6]=512*256; aa.n[7]=512*512; aa.n[8]=10*512;
    hipLaunchKernelGGL(absmax_all_k, dim3(576), dim3(256), 0, stream, aa, scales);

    PrepArgs pp;
    pp.w[0]=cw[0]; pp.w[1]=cw[1]; pp.w[2]=cw[2]; pp.w[3]=cw[3]; pp.w[4]=cw[4]; pp.w[5]=cw[5];
    pp.w[6]=fw0; pp.w[7]=fw1;
    pp.fw2 = fw2; pp.x = x;
    for (int l = 0; l < 6; ++l) { pp.bg[l]=bng[l]; pp.bb[l]=bnb[l]; pp.bm[l]=bnm[l]; pp.bv[l]=bnv[l]; }
    for (int l = 0; l < 2; ++l) { pp.bg[6+l]=fbn[l][0]; pp.bb[6+l]=fbn[l][1]; pp.bm[6+l]=fbn[l][2]; pp.bv[6+l]=fbn[l][3]; }
    {   unsigned nq = cdiv((long long)B * 1024, 256);
        hipLaunchKernelGGL(megaprep_k, dim3(NB_BPREP + NB_TERN + NB_FOLD + nq), dim3(256), 0, stream,
                           pp, scales, bfw, tf2, fold, (int*)actA, B); }

    // conv0: 4B-packed input, K=64 = ky(quad) x dx x ci4, NSTEP=1, QSTRIDE=128
    {   int NPOS = B * 900, PG = NPOS / 32, blks = (PG / 4) / 4;
        hipLaunchKernelGGL((mfconv_k<64, 1, 1, 1, 4, 32, 32, 30, 900, 2, 4, 1, 4, 4, 1, 1, 128, 1>),
                           dim3(blks), dim3(256), 0, stream, actA, bfw + 0, fold + FOLD_OFF_H[0], actB, NPOS); }
    // conv1: CI64, 30->28, CO64, J=2, ITER=1, AD=2 (R10-measured config)
    {   int NPOS = B * 784, PG = NPOS / 32, blks = PG / 4;
        hipLaunchKernelGGL((mfconv_k<64, 9, 1, 3, 64, 30, 30, 28, 784, 2, 4, 1, 4, 1, 2, 1, 16, 9>),
                           dim3(blks), dim3(256), 0, stream, actB, bfw + 4096, fold + FOLD_OFF_H[1], actA, NPOS); }
    // pool 28->14 (64ch)
    hipLaunchKernelGGL(pool_k, dim3(cdiv((long long)B * 14 * 14 * 4, 256)), dim3(256), 0, stream,
                       actA, actB, B, 64, 28, 28, 14, 14);
    // conv2: CI64, 14->12, CO128, J=2, ITER=1, AD=2
    {   int NPOS = B * 144, PG = NPOS / 32, blks = (PG * 2) / 4;
        hipLaunchKernelGGL((mfconv_k<128, 9, 1, 3, 64, 14, 14, 12, 144, 2, 4, 2, 4, 1, 2, 1, 16, 9>),
                           dim3(blks), dim3(256), 0, stream, actB, bfw + 40960, fold + FOLD_OFF_H[2], actA, NPOS); }
    // conv3: CI128, 12->10, CO128 -- NOW RESIDENT: CHP=18 (72KB LDS, 1 stage,
    // 1 barrier, AD=2 ring over 18 uninterrupted steps), MINW=2.
    {   int NPOS = B * 100, PG = NPOS / 32, blks = (PG * 2) / 4;
        hipLaunchKernelGGL((mfconv_k<128, 18, 2, 3, 128, 12, 12, 10, 100, 2, 4, 2, 2, 1, 2, 1, 16, 18>),
                           dim3(blks), dim3(256), 0, stream, actA, bfw + 114688, fold + FOLD_OFF_H[3], actB, NPOS); }
    // pool 10->5 (128ch)
    hipLaunchKernelGGL(pool_k, dim3(cdiv((long long)B * 5 * 5 * 8, 256)), dim3(256), 0, stream,
                       actB, actA, B, 128, 10, 10, 5, 5);
    // conv4: CI128, 5->3, CO256 -- NOW RESIDENT: CHP=18, AD=2, MINW=2.
    {   int NPOS = B * 9, PG = NPOS / 16, blks = (PG * 4) / 4;
        hipLaunchKernelGGL((mfconv_k<256, 18, 2, 3, 128, 5, 5, 3, 9, 1, 4, 4, 2, 1, 2, 1, 16, 18>),
                           dim3(blks), dim3(256), 0, stream, actA, bfw + 262144, fold + FOLD_OFF_H[4], actB, NPOS); }
    // conv5 as FC: I=2304, O=256 -- K-split SP=4, resident 9-step slices, AD=2
    {   int NPOS = B, PG = NPOS / 16, blks = (PG / 4) * 4 * 4;
        hipLaunchKernelGGL((mfconv_k<256, 9, 36, 1, 2304, 1, 1, 1, 1, 1, 4, 4, 4, 1, 2, 4, 16, 9>),
                           dim3(blks), dim3(256), 0, stream, actB, bfw + 557056, fold + FOLD_OFF_H[5], partW, NPOS);
        hipLaunchKernelGGL(ksum_bn_k, dim3(cdiv((long long)B * 64, 256)), dim3(256), 0, stream,
                           (const int4*)partW, fold + FOLD_OFF_H[5], actA, B, 256, 4); }
    // fc0: I=256, O=512
    {   int NPOS = B, PG = NPOS / 16, blks = (PG * 8) / 4;
        hipLaunchKernelGGL((mfconv_k<512, 4, 4, 1, 256, 1, 1, 1, 1, 1, 4, 8, 4, 1, 1, 1, 16, 4>),
                           dim3(blks), dim3(256), 0, stream, actA, bfw + 1146880, fold + FOLD_OFF_H[6], actB, NPOS); }
    // fc1: I=512, O=512
    {   int NPOS = B, PG = NPOS / 16, blks = (PG * 8) / 4;
        hipLaunchKernelGGL((mfconv_k<512, 8, 8, 1, 512, 1, 1, 1, 1, 1, 4, 8, 4, 1, 1, 1, 16, 8>),
                           dim3(blks), dim3(256), 0, stream, actB, bfw + 1277952, fold + FOLD_OFF_H[7], actA, NPOS); }
    // fc2 + tensor norm (reduces fc2 scale from partials inline)
    hipLaunchKernelGGL(fc_out_k, dim3(cdiv((long long)B * 10, 256)), dim3(256), 0, stream,
                       actA, tf2, scales, tn_w, tn_b, tn_m, tn_v,
                       (float*)d_out, B, 512, 10);
}

// Round 15
// 337.779 us; speedup vs baseline: 1.0179x; 1.0179x over previous
//
#include <hip/hip_runtime.h>
#include <stdint.h>

#define EPSF 1e-4f

typedef int v4i __attribute__((ext_vector_type(4)));

// ---------------- workspace layout (bytes) ----------------
#define OFF_SCALES 0            // 576 per-block absmax partials (9 layers x 64)
#define OFF_FOLD   4096         // folded BN params (3840 floats)
#define OFF_W      32768        // B-fragment weights (MFMA lane order)
#define OFF_TF2    (OFF_W + 1548288)   // fc2 ternary [10][512]
#define OFF_ACT_A  2097152
#define OFF_ACT_B  60817408
#define OFF_PART   134217728    // K-split i32 partials (conv5: 4.2 MB)

static const int FOLD_OFF_H[8] = {0,128,256,512,768,1280,1792,2816};
__device__ __constant__ int FOLD_OFF_D[8] = {0,128,256,512,768,1280,1792,2816};

// per-layer B-frag prep tables: l0..5 = conv0..5, l6=fc0, l7=fc1
// conv0 (mode 0) is the 4B-packed-input variant: K=64 = ky(quad) x dx x ci4
__device__ __constant__ int PREP_MODE[8] = {0,1,1,1,1,1,2,2};
__device__ __constant__ int PREP_CO[8]   = {64,64,128,128,256,256,512,512};
__device__ __constant__ int PREP_CI[8]   = {3,64,64,128,128,256,256,512};
__device__ __constant__ int PREP_KC[8]   = {1,1,1,2,2,4,1,1};
__device__ __constant__ int PREP_OFF[8]  = {0,4096,40960,114688,262144,557056,1146880,1277952};
// end of packed weights = 1540096 bytes -> 6016 blocks

#define NB_BPREP 6016
#define NB_TERN  20
#define NB_FOLD  16

// reduce a layer's 64 absmax partials (written by absmax_all_k, no atomics)
__device__ __forceinline__ float get_scale(const float* p, int l) {
    float m = p[l * 64];
#pragma unroll 63
    for (int i = 1; i < 64; ++i) m = fmaxf(m, p[l * 64 + i]);
    return m;
}

// ---------------- prep kernels ----------------
// absmax: per-block partial max -> distinct slot (no zero-init, no atomics)
struct AbsArgs { const float* w[9]; int n[9]; };
__global__ void absmax_all_k(AbsArgs a, float* partials) {
    __shared__ float red[256];
    int l = blockIdx.x >> 6;
    int sb = blockIdx.x & 63;
    const float* w = a.w[l];
    int n = a.n[l];
    float m = 0.f;
    for (int i = sb * 256 + threadIdx.x; i < n; i += 64 * 256)
        m = fmaxf(m, fabsf(w[i]));
    red[threadIdx.x] = m;
    __syncthreads();
    for (int s2 = 128; s2 > 0; s2 >>= 1) {
        if ((int)threadIdx.x < s2) red[threadIdx.x] = fmaxf(red[threadIdx.x], red[threadIdx.x + s2]);
        __syncthreads();
    }
    if (threadIdx.x == 0) partials[l * 64 + sb] = red[0];
}

// merged prep: [bprep | tern_fc2 | bnfold | quant_in] by block region.
struct PrepArgs {
    const float* w[8];        // conv0..5, fc0, fc1
    const float* fw2;
    const float* x;           // input images
    const float* bg[8]; const float* bb[8]; const float* bm[8]; const float* bv[8];
};
__global__ void megaprep_k(PrepArgs pa, const float* __restrict__ partials,
                           int8_t* __restrict__ dst, int8_t* __restrict__ tf2,
                           float* __restrict__ fold, int* __restrict__ qout, int B) {
    int b = blockIdx.x;
    if (b < NB_BPREP) {
        int gidx = b * 256 + threadIdx.x;
        int l = 0;
#pragma unroll
        for (int i = 1; i < 8; ++i) l += (gidx >= PREP_OFF[i]) ? 1 : 0;
        int idx = gidx - PREP_OFF[l];
        const float* w = pa.w[l];
        float s = get_scale(partials, l);
        int jb = idx & 15;
        int lane = (idx >> 4) & 63;
        int fct = idx >> 10;
        int quad = lane >> 4, n = lane & 15;
        int COT = PREP_CO[l] >> 4;
        int ct = fct & (COT - 1);
        int st = fct >> (31 - __clz(COT));
        int co = (ct >> 2) * 64 + (ct & 3) + 4 * n;   // ct-interleaved
        float val;
        int md = PREP_MODE[l];
        if (md == 0) {
            int ky = quad, dx = jb >> 2, ci = jb & 3;
            val = (ky < 3 && dx < 3 && ci < 3) ? w[(co * 3 + ci) * 9 + ky * 3 + dx] : 0.f;
        } else if (md == 1) {
            int KC = PREP_KC[l], CI = PREP_CI[l];
            int kxy = st / KC, kc = st - kxy * KC;
            int ci = kc * 64 + quad * 16 + jb;
            val = w[(co * CI + ci) * 9 + kxy];
        } else {
            int CI = PREP_CI[l];
            int i = st * 64 + quad * 16 + jb;
            val = w[co * CI + i];
        }
        float q = fminf(fmaxf(rintf(val / s), -1.f), 1.f);
        dst[gidx] = (int8_t)q;
    } else if (b < NB_BPREP + NB_TERN) {
        int i = (b - NB_BPREP) * 256 + threadIdx.x;   // < 5120 exact
        float s = get_scale(partials, 8);
        float q = fminf(fmaxf(rintf(pa.fw2[i] / s), -1.f), 1.f);
        tf2[i] = (int8_t)q;
    } else if (b < NB_BPREP + NB_TERN + NB_FOLD) {
        int rel = b - NB_BPREP - NB_TERN;             // 0..15
        int l = rel >> 1;
        int i = (rel & 1) * 256 + threadIdx.x;
        int CO = PREP_CO[l];
        if (i >= CO) return;
        float s = get_scale(partials, l);
        float sc = pa.bg[l][i] / sqrtf(pa.bv[l][i] + EPSF);
        float s_in = (l == 0) ? 0.0078125f : 1.0f;
        fold[FOLD_OFF_D[l] + i] = s_in * s * sc;
        fold[FOLD_OFF_D[l] + CO + i] = pa.bb[l][i] - pa.bm[l][i] * sc;
    } else {
        int idx = (b - NB_BPREP - NB_TERN - NB_FOLD) * 256 + threadIdx.x;
        if (idx >= B * 1024) return;
        int p = idx & 1023;
        int bb2 = idx >> 10;
        unsigned pk = 0;
#pragma unroll
        for (int c = 0; c < 3; ++c) {
            float q = rintf(pa.x[((size_t)bb2 * 3 + c) * 1024 + p] * 128.f);
            q = fminf(fmaxf(q, -127.f), 127.f);
            pk |= ((unsigned)((int)q & 0xff)) << (8 * c);
        }
        qout[idx] = (int)pk;
    }
}

// K-split reduce: sum SP i32 partials, BN + 2-bit quant, pack 4 co/dword.
__global__ void ksum_bn_k(const int4* __restrict__ part, const float* __restrict__ fold,
                          int8_t* __restrict__ out, int NPOS, int CO, int SP) {
    int idx = blockIdx.x * 256 + threadIdx.x;
    int n4 = CO >> 2;
    if (idx >= NPOS * n4) return;
    int c4 = idx % n4, pos = idx / n4;
    int4 s = make_int4(0, 0, 0, 0);
    for (int sp = 0; sp < SP; ++sp) {
        int4 p = part[(size_t)(sp * NPOS + pos) * n4 + c4];
        s.x += p.x; s.y += p.y; s.z += p.z; s.w += p.w;
    }
    int co = c4 * 4;
    const int* sv = (const int*)&s;
    unsigned pk = 0;
#pragma unroll
    for (int k = 0; k < 4; ++k) {
        float h = (float)sv[k] * fold[co + k] + fold[CO + co + k];
        int q = (int)fminf(fmaxf(rintf(h), -1.f), 1.f);
        pk |= ((unsigned)(q & 0xff)) << (8 * k);
    }
    *(int*)&out[(size_t)pos * CO + co] = (int)pk;
}

// ---------------- MFMA implicit-GEMM conv/FC (R13-passing template) ----------------
// Session-final per-layer configs; each won a controlled comparison:
//   conv0: 4B-packed K-geometry (R12), J=2/ITER=4 (R7)
//   conv1/conv2: J=2, AD=2, full grid (R10; ITER falsified R8, A-in-LDS
//     falsified R11, resident-72KB falsified R14)
//   conv3/conv4: chunked CHP=9 (resident-72KB regressed in R14: LDS->2
//     blocks/CU lost more residency-overlap than 1-barrier saved)
//   conv5: K-split SP=4 + ksum (R10)
template<int CO, int NSTEP, int KC, int KXN, int CI, int IH, int IW, int OW,
         int NPOS1, int J, int NCT, int COG, int MINW, int ITER, int AD, int SP,
         int QSTRIDE>
__global__ __launch_bounds__(256, MINW) void mfconv_k(
        const int8_t* __restrict__ act, const int8_t* __restrict__ bf,
        const float* __restrict__ fold, int8_t* __restrict__ out, int NPOS) {
    static_assert(NCT == 4, "epilogue packs 4 cotiles per dword");
    constexpr int COT = CO / 16;
    constexpr int CH = NSTEP < 9 ? NSTEP : 9;     // steps per LDS chunk
    constexpr int NCHK = NSTEP / CH;              // all configs: NSTEP % CH == 0
    static_assert(AD == 1 || AD == 2, "A-lookahead depth");
    static_assert((ITER == 1 && AD == 1) || NCHK == 1,
                  "ITER/AD need resident B");
    static_assert(AD == 1 || NSTEP % 3 == 0, "ring-3 phase proof");
    static_assert(ITER == 1 || AD == 2 || (NSTEP & 1) == 1,
                  "AD=1 ITER path needs odd NSTEP (buffer parity proof)");
    static_assert(SP == 1 || (NCHK == 1 && ITER == 1), "K-split: resident B");
    __shared__ __align__(16) int8_t lds[CH * NCT * 1024];

    int lane = threadIdx.x & 63;
    int wid = threadIdx.x >> 6;
    int nb = (int)gridDim.x;
    int b0 = (int)blockIdx.x;
    int bsw = (nb & 7) ? b0 : ((b0 & 7) * (nb >> 3) + (b0 >> 3));
    int w = bsw * 4 + wid;                        // grid is exact: no tail waves
    int PGi = NPOS / (16 * J) / ITER;             // pg-groups per wave
    int pgw = w % PGi;
    int cgsp = w / PGi;
    int cg = cgsp % COG;                          // block-uniform (PGi%4==0)
    int sp = cgsp / COG;                          // block-uniform K-split slot
    constexpr int sStep = NSTEP;
    int sBase = sp * sStep;
    int m = lane & 15, quad = lane >> 4;

    float Af[NCT], Bf[NCT];
#pragma unroll
    for (int ct = 0; ct < NCT; ++ct) {
        int co = cg * 64 + ct + 4 * m;
        Af[ct] = fold[co];
        Bf[ct] = fold[CO + co];
    }

    const int8_t* ab[J];
    auto setA = [&](int pos0) {
#pragma unroll
        for (int j = 0; j < J; ++j) {
            int pos = pos0 + j * 16 + m;
            int img = pos / NPOS1, p = pos - img * NPOS1;
            int oy = p / OW, ox = p - oy * OW;
            ab[j] = act + (size_t)((img * IH + oy) * IW + ox) * CI + quad * QSTRIDE;
        }
    };
    auto ldA = [&](int s, v4i* dst) {             // s is ABSOLUTE step
        int kxy = s / KC, kc = s - kxy * KC;
        int ky = kxy / KXN, kx = kxy - ky * KXN;
        int off = (ky * IW + kx) * CI + kc * 64;
#pragma unroll
        for (int j = 0; j < J; ++j) dst[j] = *(const v4i*)(ab[j] + off);
    };
    auto ldB = [&](int ls, v4i* dst) {            // ls is LOCAL (LDS slot)
#pragma unroll
        for (int ct = 0; ct < NCT; ++ct)
            dst[ct] = *(const v4i*)&lds[(ls * NCT + ct) * 1024 + lane * 16];
    };
    auto stageB = [&](int s0) {                   // s0 is ABSOLUTE
#pragma unroll
        for (int ls = 0; ls < CH; ++ls) {
            const int8_t* src = bf + ((size_t)((s0 + ls) * COT) + cg * NCT) * 1024;
#pragma unroll
            for (int k = 0; k < NCT / 4; ++k)
                *(v4i*)&lds[ls * NCT * 1024 + (k * 256 + (int)threadIdx.x) * 16] =
                    *(const v4i*)(src + (k * 256 + (int)threadIdx.x) * 16);
        }
    };
    auto finish = [&](int pos0, v4i (&acc)[J][NCT]) {
        if (SP == 1) {
#pragma unroll
            for (int j = 0; j < J; ++j) {
#pragma unroll
                for (int r = 0; r < 4; ++r) {
                    unsigned pk = 0;
#pragma unroll
                    for (int ct = 0; ct < NCT; ++ct) {
                        float h = (float)acc[j][ct][r] * Af[ct] + Bf[ct];
                        int q = (int)fminf(fmaxf(rintf(h), -1.f), 1.f);
                        pk |= ((unsigned)(q & 0xff)) << (8 * ct);
                    }
                    *(int*)&out[(size_t)(pos0 + j * 16 + quad * 4 + r) * CO + cg * 64 + 4 * m] = (int)pk;
                }
            }
        } else {
            int* part = (int*)out;
#pragma unroll
            for (int j = 0; j < J; ++j) {
#pragma unroll
                for (int r = 0; r < 4; ++r) {
                    v4i pv;
#pragma unroll
                    for (int ct = 0; ct < NCT; ++ct) pv[ct] = acc[j][ct][r];
                    *(v4i*)&part[(size_t)(sp * NPOS + pos0 + j * 16 + quad * 4 + r) * CO + cg * 64 + 4 * m] = pv;
                }
            }
        }
    };

    v4i Ab[3][J], Bb[2][NCT];

    if (NCHK == 1) {
        int pg = pgw * ITER;
        int pos0 = pg * (16 * J);
        setA(pos0);
        ldA(sBase + 0, Ab[0]);
        if (AD == 2 && NSTEP > 1) ldA(sBase + 1, Ab[1]);
        stageB(sBase);
        __syncthreads();                          // the ONLY barrier
#pragma unroll
        for (int it = 0; it < ITER; ++it) {
            v4i acc[J][NCT] = {};
            ldB(0, Bb[0]);
            if (AD == 2) {
#pragma unroll
                for (int ls = 0; ls < NSTEP; ++ls) {
                    if (ls + 2 < NSTEP) ldA(sBase + ls + 2, Ab[(ls + 2) % 3]);
                    if (ls + 1 < NSTEP) ldB(ls + 1, Bb[(ls + 1) & 1]);
                    __builtin_amdgcn_sched_barrier(0);
#pragma unroll
                    for (int j = 0; j < J; ++j)
#pragma unroll
                        for (int ct = 0; ct < NCT; ++ct)
                            acc[j][ct] = __builtin_amdgcn_mfma_i32_16x16x64_i8(
                                Ab[ls % 3][j], Bb[ls & 1][ct], acc[j][ct], 0, 0, 0);
                }
                int pos0n = pos0;
                if (it + 1 < ITER) {
                    pos0n = (pg + it + 1) * (16 * J);
                    setA(pos0n);
                    ldA(sBase + 0, Ab[0]);
                    ldA(sBase + 1, Ab[1]);
                }
                __builtin_amdgcn_sched_barrier(0);
                finish(pos0, acc);
                pos0 = pos0n;
            } else {
                const int p = (it & 1) & (NSTEP & 1);
#pragma unroll
                for (int ls = 0; ls < NSTEP; ++ls) {
                    if (ls + 1 < NSTEP) {
                        ldA(sBase + ls + 1, Ab[(ls + 1 + p) & 1]);
                        ldB(ls + 1, Bb[(ls + 1) & 1]);
                    }
                    __builtin_amdgcn_sched_barrier(0);
#pragma unroll
                    for (int j = 0; j < J; ++j)
#pragma unroll
                        for (int ct = 0; ct < NCT; ++ct)
                            acc[j][ct] = __builtin_amdgcn_mfma_i32_16x16x64_i8(
                                Ab[(ls + p) & 1][j], Bb[ls & 1][ct], acc[j][ct], 0, 0, 0);
                }
                int pos0n = pos0;
                if (it + 1 < ITER) {
                    pos0n = (pg + it + 1) * (16 * J);
                    setA(pos0n);
                    ldA(sBase + 0, Ab[(p ^ 1) & 1]);
                }
                __builtin_amdgcn_sched_barrier(0);
                finish(pos0, acc);
                pos0 = pos0n;
            }
        }
    } else {
        int pos0 = pgw * (16 * J);
        setA(pos0);
        v4i acc[J][NCT] = {};
#pragma unroll
        for (int c = 0; c < NCHK; ++c) {
            int s0 = c * CH;
            ldA(s0, Ab[s0 & 1]);
            __syncthreads();
            stageB(s0);
            __syncthreads();
            ldB(0, Bb[0]);
#pragma unroll
            for (int ls = 0; ls < CH; ++ls) {
                int s = s0 + ls;
                int cb = s & 1, nb2 = cb ^ 1;
                if (ls + 1 < CH) {
                    ldA(s + 1, Ab[nb2]);
                    ldB(ls + 1, Bb[(ls + 1) & 1]);
                }
                __builtin_amdgcn_sched_barrier(0);
#pragma unroll
                for (int j = 0; j < J; ++j)
#pragma unroll
                    for (int ct = 0; ct < NCT; ++ct)
                        acc[j][ct] = __builtin_amdgcn_mfma_i32_16x16x64_i8(
                            Ab[cb][j], Bb[ls & 1][ct], acc[j][ct], 0, 0, 0);
            }
        }
        finish(pos0, acc);
    }
}

// ---------------- pool (int4: 16 channels per thread) ----------------
__global__ void pool_k(const int8_t* __restrict__ a, int8_t* __restrict__ o,
                       int B, int C, int IH, int IW, int OH, int OW) {
    int idx = blockIdx.x * blockDim.x + threadIdx.x;
    int c16n = C >> 4;
    int total = B * OH * OW * c16n;
    if (idx >= total) return;
    int c16 = idx % c16n;
    int t1 = idx / c16n;
    int ox = t1 % OW;
    int t2 = t1 / OW;
    int oy = t2 % OH;
    int b = t2 / OH;
    const int8_t* p = a + (((size_t)b * IH + 2 * oy) * IW + 2 * ox) * C + 16 * c16;
    int4 w0 = *(const int4*)p;
    int4 w1 = *(const int4*)(p + C);
    int4 w2 = *(const int4*)(p + (size_t)IW * C);
    int4 w3 = *(const int4*)(p + (size_t)IW * C + C);
    int4 r;
    const int* a0 = (const int*)&w0; const int* a1 = (const int*)&w1;
    const int* a2 = (const int*)&w2; const int* a3 = (const int*)&w3;
    int* rr = (int*)&r;
#pragma unroll
    for (int d = 0; d < 4; ++d) {
        unsigned v = 0;
#pragma unroll
        for (int k = 0; k < 4; ++k) {
            int x0 = (int)(int8_t)(a0[d] >> (8 * k));
            int x1 = (int)(int8_t)(a1[d] >> (8 * k));
            int x2 = (int)(int8_t)(a2[d] >> (8 * k));
            int x3 = (int)(int8_t)(a3[d] >> (8 * k));
            int mx = max(max(x0, x1), max(x2, x3));
            v |= ((unsigned)(mx & 0xff)) << (8 * k);
        }
        rr[d] = (int)v;
    }
    *(int4*)(o + (((size_t)b * OH + oy) * OW + ox) * C + 16 * c16) = r;
}

__device__ __forceinline__ int dot4(int a, int b, int c) {
#if __has_builtin(__builtin_amdgcn_sdot4)
    return __builtin_amdgcn_sdot4(a, b, c, false);
#else
    c += (int)(int8_t)(a) * (int)(int8_t)(b);
    c += (int)(int8_t)(a >> 8)  * (int)(int8_t)(b >> 8);
    c += (int)(int8_t)(a >> 16) * (int)(int8_t)(b >> 16);
    c += (int)(int8_t)(a >> 24) * (int)(int8_t)(b >> 24);
    return c;
#endif
}

// final FC + tensor norm -> float out; reduces fc2 scale from partials inline
__global__ void fc_out_k(const int8_t* __restrict__ a, const int8_t* __restrict__ t,
                         const float* __restrict__ partials,
                         const float* __restrict__ tw, const float* __restrict__ tb,
                         const float* __restrict__ tm, const float* __restrict__ tv,
                         float* __restrict__ out, int B, int I, int O) {
    int idx = blockIdx.x * blockDim.x + threadIdx.x;
    if (idx >= B * O) return;
    int o = idx % O;
    int b = idx / O;
    const int* ar = (const int*)(a + (size_t)b * I);
    const int* tr = (const int*)(t + (size_t)o * I);
    int acc = 0;
    for (int i = 0; i < (I >> 2); ++i) acc = dot4(ar[i], tr[i], acc);
    float s8 = get_scale(partials, 8);
    float sc = tw[0] / sqrtf(tv[0] + EPSF);
    out[idx] = ((float)acc * s8 - tm[0]) * sc + tb[0];
}

static inline unsigned cdiv(long long a, int b) { return (unsigned)((a + b - 1) / b); }

extern "C" void kernel_launch(void* const* d_in, const int* in_sizes, int n_in,
                              void* d_out, int out_size, void* d_ws, size_t ws_size,
                              hipStream_t stream) {
    const float* x = (const float*)d_in[0];
    const float* cw[6]; const float* bng[6]; const float* bnb[6];
    const float* bnm[6]; const float* bnv[6];
    for (int l = 0; l < 6; ++l) {
        cw[l]  = (const float*)d_in[1 + 5 * l + 0];
        bng[l] = (const float*)d_in[1 + 5 * l + 1];
        bnb[l] = (const float*)d_in[1 + 5 * l + 2];
        bnm[l] = (const float*)d_in[1 + 5 * l + 3];
        bnv[l] = (const float*)d_in[1 + 5 * l + 4];
    }
    const float* fw0 = (const float*)d_in[31];
    const float* fw1 = (const float*)d_in[32];
    const float* fw2 = (const float*)d_in[33];
    const float* fbn[2][4] = {
        { (const float*)d_in[34], (const float*)d_in[35], (const float*)d_in[36], (const float*)d_in[37] },
        { (const float*)d_in[38], (const float*)d_in[39], (const float*)d_in[40], (const float*)d_in[41] } };
    const float* tn_w = (const float*)d_in[42];
    const float* tn_b = (const float*)d_in[43];
    const float* tn_m = (const float*)d_in[44];
    const float* tn_v = (const float*)d_in[45];

    char* ws = (char*)d_ws;
    float* scales = (float*)(ws + OFF_SCALES);    // 576 partials
    float* fold = (float*)(ws + OFF_FOLD);
    int8_t* bfw = (int8_t*)(ws + OFF_W);
    int8_t* tf2 = (int8_t*)(ws + OFF_TF2);
    int8_t* actA = (int8_t*)(ws + OFF_ACT_A);
    int8_t* actB = (int8_t*)(ws + OFF_ACT_B);
    int8_t* partW = (int8_t*)(ws + OFF_PART);

    const int B = in_sizes[0] / 3072;

    AbsArgs aa;
    aa.w[0]=cw[0]; aa.w[1]=cw[1]; aa.w[2]=cw[2]; aa.w[3]=cw[3]; aa.w[4]=cw[4]; aa.w[5]=cw[5];
    aa.w[6]=fw0; aa.w[7]=fw1; aa.w[8]=fw2;
    aa.n[0]=64*3*9; aa.n[1]=64*64*9; aa.n[2]=128*64*9; aa.n[3]=128*128*9;
    aa.n[4]=256*128*9; aa.n[5]=256*256*9; aa.n[6]=512*256; aa.n[7]=512*512; aa.n[8]=10*512;
    hipLaunchKernelGGL(absmax_all_k, dim3(576), dim3(256), 0, stream, aa, scales);

    PrepArgs pp;
    pp.w[0]=cw[0]; pp.w[1]=cw[1]; pp.w[2]=cw[2]; pp.w[3]=cw[3]; pp.w[4]=cw[4]; pp.w[5]=cw[5];
    pp.w[6]=fw0; pp.w[7]=fw1;
    pp.fw2 = fw2; pp.x = x;
    for (int l = 0; l < 6; ++l) { pp.bg[l]=bng[l]; pp.bb[l]=bnb[l]; pp.bm[l]=bnm[l]; pp.bv[l]=bnv[l]; }
    for (int l = 0; l < 2; ++l) { pp.bg[6+l]=fbn[l][0]; pp.bb[6+l]=fbn[l][1]; pp.bm[6+l]=fbn[l][2]; pp.bv[6+l]=fbn[l][3]; }
    {   unsigned nq = cdiv((long long)B * 1024, 256);
        hipLaunchKernelGGL(megaprep_k, dim3(NB_BPREP + NB_TERN + NB_FOLD + nq), dim3(256), 0, stream,
                           pp, scales, bfw, tf2, fold, (int*)actA, B); }

    // conv0: 4B-packed input, K=64 = ky(quad) x dx x ci4, NSTEP=1, QSTRIDE=128
    {   int NPOS = B * 900, PG = NPOS / 32, blks = (PG / 4) / 4;
        hipLaunchKernelGGL((mfconv_k<64, 1, 1, 1, 4, 32, 32, 30, 900, 2, 4, 1, 4, 4, 1, 1, 128>),
                           dim3(blks), dim3(256), 0, stream, actA, bfw + 0, fold + FOLD_OFF_H[0], actB, NPOS); }
    // conv1: CI64, 30->28, CO64, J=2, ITER=1, AD=2 (R10-measured config)
    {   int NPOS = B * 784, PG = NPOS / 32, blks = PG / 4;
        hipLaunchKernelGGL((mfconv_k<64, 9, 1, 3, 64, 30, 30, 28, 784, 2, 4, 1, 4, 1, 2, 1, 16>),
                           dim3(blks), dim3(256), 0, stream, actB, bfw + 4096, fold + FOLD_OFF_H[1], actA, NPOS); }
    // pool 28->14 (64ch)
    hipLaunchKernelGGL(pool_k, dim3(cdiv((long long)B * 14 * 14 * 4, 256)), dim3(256), 0, stream,
                       actA, actB, B, 64, 28, 28, 14, 14);
    // conv2: CI64, 14->12, CO128, J=2, ITER=1, AD=2
    {   int NPOS = B * 144, PG = NPOS / 32, blks = (PG * 2) / 4;
        hipLaunchKernelGGL((mfconv_k<128, 9, 1, 3, 64, 14, 14, 12, 144, 2, 4, 2, 4, 1, 2, 1, 16>),
                           dim3(blks), dim3(256), 0, stream, actB, bfw + 40960, fold + FOLD_OFF_H[2], actA, NPOS); }
    // conv3: CI128, 12->10, CO128, J=2 (chunked CHP=9, ITER=1, AD=1 -- R13)
    {   int NPOS = B * 100, PG = NPOS / 32, blks = (PG * 2) / 4;
        hipLaunchKernelGGL((mfconv_k<128, 18, 2, 3, 128, 12, 12, 10, 100, 2, 4, 2, 4, 1, 1, 1, 16>),
                           dim3(blks), dim3(256), 0, stream, actA, bfw + 114688, fold + FOLD_OFF_H[3], actB, NPOS); }
    // pool 10->5 (128ch)
    hipLaunchKernelGGL(pool_k, dim3(cdiv((long long)B * 5 * 5 * 8, 256)), dim3(256), 0, stream,
                       actB, actA, B, 128, 10, 10, 5, 5);
    // conv4: CI128, 5->3, CO256 (chunked CHP=9 -- R13)
    {   int NPOS = B * 9, PG = NPOS / 16, blks = (PG * 4) / 4;
        hipLaunchKernelGGL((mfconv_k<256, 18, 2, 3, 128, 5, 5, 3, 9, 1, 4, 4, 4, 1, 1, 1, 16>),
                           dim3(blks), dim3(256), 0, stream, actA, bfw + 262144, fold + FOLD_OFF_H[4], actB, NPOS); }
    // conv5 as FC: I=2304, O=256 -- K-split SP=4, resident 9-step slices, AD=2
    {   int NPOS = B, PG = NPOS / 16, blks = (PG / 4) * 4 * 4;
        hipLaunchKernelGGL((mfconv_k<256, 9, 36, 1, 2304, 1, 1, 1, 1, 1, 4, 4, 4, 1, 2, 4, 16>),
                           dim3(blks), dim3(256), 0, stream, actB, bfw + 557056, fold + FOLD_OFF_H[5], partW, NPOS);
        hipLaunchKernelGGL(ksum_bn_k, dim3(cdiv((long long)B * 64, 256)), dim3(256), 0, stream,
                           (const int4*)partW, fold + FOLD_OFF_H[5], actA, B, 256, 4); }
    // fc0: I=256, O=512
    {   int NPOS = B, PG = NPOS / 16, blks = (PG * 8) / 4;
        hipLaunchKernelGGL((mfconv_k<512, 4, 4, 1, 256, 1, 1, 1, 1, 1, 4, 8, 4, 1, 1, 1, 16>),
                           dim3(blks), dim3(256), 0, stream, actA, bfw + 1146880, fold + FOLD_OFF_H[6], actB, NPOS); }
    // fc1: I=512, O=512
    {   int NPOS = B, PG = NPOS / 16, blks = (PG * 8) / 4;
        hipLaunchKernelGGL((mfconv_k<512, 8, 8, 1, 512, 1, 1, 1, 1, 1, 4, 8, 4, 1, 1, 1, 16>),
                           dim3(blks), dim3(256), 0, stream, actB, bfw + 1277952, fold + FOLD_OFF_H[7], actA, NPOS); }
    // fc2 + tensor norm (reduces fc2 scale from partials inline)
    hipLaunchKernelGGL(fc_out_k, dim3(cdiv((long long)B * 10, 256)), dim3(256), 0, stream,
                       actA, tf2, scales, tn_w, tn_b, tn_m, tn_v,
                       (float*)d_out, B, 512, 10);
}